// Round 8
// baseline (627.379 us; speedup 1.0000x reference)
//
#include <hip/hip_runtime.h>
#include <math.h>

#define N_NODES 100000
#define FDIM 128
#define E_EDGES 1600000
#define NSCAN_BLKS ((N_NODES + 1023) / 1024)   // 98
#define NPASS 8
#define PASS_NODES 12500                        // N_NODES / NPASS exactly

typedef unsigned short bf16_t;
typedef __attribute__((ext_vector_type(8))) short short8;
typedef __attribute__((ext_vector_type(4))) float f32x4;

__device__ inline bf16_t f2bf(float f) {
    unsigned int u = __float_as_uint(f);
    return (bf16_t)((u + 0x7fffu + ((u >> 16) & 1u)) >> 16);   // RNE
}
__device__ inline float bf2f(bf16_t u) {
    return __uint_as_float(((unsigned)u) << 16);
}
// unpack uint (2 packed bf16) -> float2 (x = low element = even col)
__device__ inline float2 bfpair(unsigned int u) {
    return make_float2(__uint_as_float(u << 16), __uint_as_float(u & 0xffff0000u));
}

// ---------------- in-degree histogram, range-partitioned (XCD-local) -------
__global__ __launch_bounds__(256) void hist_kernel(const int* __restrict__ dst,
                                                   int* __restrict__ cnt) {
    int pass = blockIdx.x & (NPASS - 1);
    int e = (blockIdx.x >> 3) * 256 + threadIdx.x;
    if (e >= E_EDGES) return;
    int d = dst[e];
    if ((unsigned)(d - pass * PASS_NODES) < (unsigned)PASS_NODES)
        atomicAdd(&cnt[d], 1);
}

// ---------------- 3-phase exclusive scan: cnt -> rowptr ----------------
__global__ __launch_bounds__(256) void scan1(const int* __restrict__ cnt,
                                             int* __restrict__ excl,
                                             int* __restrict__ bsum) {
    __shared__ int lds[256];
    const int b = blockIdx.x, t = threadIdx.x;
    const int base = b * 1024 + t * 4;
    int v[4];
#pragma unroll
    for (int q = 0; q < 4; ++q) {
        int i = base + q;
        v[q] = (i < N_NODES) ? cnt[i] : 0;
    }
    int tsum = v[0] + v[1] + v[2] + v[3];
    lds[t] = tsum;
    __syncthreads();
    for (int off = 1; off < 256; off <<= 1) {
        int x = lds[t];
        int y = (t >= off) ? lds[t - off] : 0;
        __syncthreads();
        lds[t] = x + y;
        __syncthreads();
    }
    int texcl = lds[t] - tsum;
    if (t == 255) bsum[b] = lds[t];
    int run = texcl;
#pragma unroll
    for (int q = 0; q < 4; ++q) {
        int i = base + q;
        if (i < N_NODES) excl[i] = run;
        run += v[q];
    }
}

__global__ __launch_bounds__(128) void scan2(int* __restrict__ bsum) {
    __shared__ int lds[128];
    const int t = threadIdx.x;
    int v = (t < NSCAN_BLKS) ? bsum[t] : 0;
    lds[t] = v;
    __syncthreads();
    for (int off = 1; off < 128; off <<= 1) {
        int x = lds[t];
        int y = (t >= off) ? lds[t - off] : 0;
        __syncthreads();
        lds[t] = x + y;
        __syncthreads();
    }
    if (t < NSCAN_BLKS) bsum[t] = lds[t] - v;   // exclusive
}

// add block offsets + compute dinv + close rowptr
__global__ __launch_bounds__(256) void scan3(int* __restrict__ rowptr,
                                             const int* __restrict__ bsum,
                                             const int* __restrict__ cnt,
                                             float* __restrict__ dinv) {
    int i = blockIdx.x * blockDim.x + threadIdx.x;
    if (i < N_NODES) {
        rowptr[i] += bsum[i >> 10];
        dinv[i] = rsqrtf((float)cnt[i] + 1.0f);
    }
    if (i == 0) rowptr[N_NODES] = E_EDGES;
}

// ------- scatter edges, range-partitioned; store {src, norm} per slot ------
__global__ __launch_bounds__(256) void scatter_kernel(const int* __restrict__ src,
                                                      const int* __restrict__ dst,
                                                      const int* __restrict__ rowptr,
                                                      const float* __restrict__ dinv,
                                                      int* __restrict__ cursor,
                                                      int2* __restrict__ emeta) {
    int pass = blockIdx.x & (NPASS - 1);
    int e = (blockIdx.x >> 3) * 256 + threadIdx.x;
    if (e >= E_EDGES) return;
    int d = dst[e];
    if ((unsigned)(d - pass * PASS_NODES) < (unsigned)PASS_NODES) {
        int s = src[e];
        int p = rowptr[d] + atomicAdd(&cursor[d], 1);
        float nrm = dinv[s] * dinv[d];
        emeta[p] = make_int2(s, __float_as_int(nrm));
    }
}

// ---------------- W [k][c] fp32 -> Wt [c][k] bf16 (B^T layout) ------------
__global__ __launch_bounds__(256) void wcvt_kernel(const float* __restrict__ W,
                                                   bf16_t* __restrict__ Wt) {
    int idx = blockIdx.x * 256 + threadIdx.x;   // over 16384
    int k = idx >> 7, c = idx & 127;
    Wt[c * 128 + k] = f2bf(W[idx]);
}

// ---------------- MFMA GEMM: H(bf16) = A @ Wt^T ----------------
template <bool A_IS_F32>
__global__ __launch_bounds__(256) void gemm_mfma(const void* __restrict__ Aptr,
                                                 const bf16_t* __restrict__ Wt,
                                                 bf16_t* __restrict__ H) {
    const int tid = threadIdx.x;
    const int wave = tid >> 6;
    const int l = tid & 63;
    const int r = l & 15;          // A row / B col within tile
    const int g = l >> 4;          // k-group (0..3)
    const int row0 = (blockIdx.x * 4 + wave) * 16;
    const int arow = min(row0 + r, N_NODES - 1);

    f32x4 acc[8];
#pragma unroll
    for (int ct = 0; ct < 8; ++ct) acc[ct] = (f32x4){0.f, 0.f, 0.f, 0.f};

#pragma unroll
    for (int ks = 0; ks < 4; ++ks) {
        const int kbase = ks * 32 + g * 8;
        short8 a;
        if constexpr (A_IS_F32) {
            const float* X = (const float*)Aptr;
            const float4 x0 = *((const float4*)(X + (size_t)arow * 128 + kbase));
            const float4 x1 = *((const float4*)(X + (size_t)arow * 128 + kbase + 4));
            a[0] = (short)f2bf(x0.x); a[1] = (short)f2bf(x0.y);
            a[2] = (short)f2bf(x0.z); a[3] = (short)f2bf(x0.w);
            a[4] = (short)f2bf(x1.x); a[5] = (short)f2bf(x1.y);
            a[6] = (short)f2bf(x1.z); a[7] = (short)f2bf(x1.w);
        } else {
            const bf16_t* X = (const bf16_t*)Aptr;
            a = *((const short8*)(X + (size_t)arow * 128 + kbase));
        }
#pragma unroll
        for (int ct = 0; ct < 8; ++ct) {
            short8 b = *((const short8*)(Wt + (ct * 16 + r) * 128 + kbase));
            acc[ct] = __builtin_amdgcn_mfma_f32_16x16x32_bf16(a, b, acc[ct], 0, 0, 0);
        }
    }

    // epilogue: D[row=(l>>4)*4+j][col=ct*16+r]
#pragma unroll
    for (int j = 0; j < 4; ++j) {
        const int row = row0 + g * 4 + j;
        if (row < N_NODES) {
            bf16_t* hp = H + (size_t)row * 128 + r;
#pragma unroll
            for (int ct = 0; ct < 8; ++ct) hp[ct * 16] = f2bf(acc[ct][j]);
        }
    }
}

// ------- feature-split gather-aggregate: wave = (node, half-of-features) ---
// blockIdx%8 in {0..3} -> half0 on XCDs 0-3; {4..7} -> half1 on XCDs 4-7.
// Each XCD's L2 only ever sees 12.8 MB of h. 1 bf16/lane, unroll 8 with
// explicit next-batch meta prefetch.
__global__ __launch_bounds__(256) void agg_half_kernel(const int* __restrict__ rowptr,
                                                       const int2* __restrict__ emeta,
                                                       const float* __restrict__ dinv,
                                                       const bf16_t* __restrict__ h,
                                                       const float* __restrict__ bias,
                                                       bf16_t* __restrict__ out) {
    const int b = blockIdx.x;
    const int wave = threadIdx.x >> 6;
    const int lane = threadIdx.x & 63;
    const int half = (b >> 2) & 1;              // period-8 in blockIdx
    const int idx  = (b >> 3) * 4 + (b & 3);    // dense in [0,25000) per half
    const int node = idx * 4 + wave;
    if (node >= N_NODES) return;
    const int f = half * 64 + lane;
    const bf16_t* __restrict__ hc = h + f;

    float dd = dinv[node];
    float acc = dd * dd * bf2f(hc[(size_t)node * 128]);

    int j = rowptr[node];
    const int end = rowptr[node + 1];

    int2 m0, m1, m2, m3, m4, m5, m6, m7;
    bool have = (j + 8 <= end);
    if (have) {
        m0 = emeta[j + 0]; m1 = emeta[j + 1]; m2 = emeta[j + 2]; m3 = emeta[j + 3];
        m4 = emeta[j + 4]; m5 = emeta[j + 5]; m6 = emeta[j + 6]; m7 = emeta[j + 7];
    }
    while (have) {
        const int jn = j + 8;
        const bool nxt = (jn + 8 <= end);
        int2 t0, t1, t2, t3, t4, t5, t6, t7;
        if (nxt) {   // prefetch next batch while rows of this batch are in flight
            t0 = emeta[jn + 0]; t1 = emeta[jn + 1]; t2 = emeta[jn + 2]; t3 = emeta[jn + 3];
            t4 = emeta[jn + 4]; t5 = emeta[jn + 5]; t6 = emeta[jn + 6]; t7 = emeta[jn + 7];
        }
        float v0 = bf2f(hc[(size_t)m0.x * 128]);
        float v1 = bf2f(hc[(size_t)m1.x * 128]);
        float v2 = bf2f(hc[(size_t)m2.x * 128]);
        float v3 = bf2f(hc[(size_t)m3.x * 128]);
        float v4 = bf2f(hc[(size_t)m4.x * 128]);
        float v5 = bf2f(hc[(size_t)m5.x * 128]);
        float v6 = bf2f(hc[(size_t)m6.x * 128]);
        float v7 = bf2f(hc[(size_t)m7.x * 128]);
        acc += v0 * __int_as_float(m0.y) + v1 * __int_as_float(m1.y)
             + v2 * __int_as_float(m2.y) + v3 * __int_as_float(m3.y)
             + v4 * __int_as_float(m4.y) + v5 * __int_as_float(m5.y)
             + v6 * __int_as_float(m6.y) + v7 * __int_as_float(m7.y);
        j = jn;
        have = nxt;
        if (nxt) {
            m0 = t0; m1 = t1; m2 = t2; m3 = t3;
            m4 = t4; m5 = t5; m6 = t6; m7 = t7;
        }
    }
    for (; j < end; ++j) {
        int2 m = emeta[j];
        acc += bf2f(hc[(size_t)m.x * 128]) * __int_as_float(m.y);
    }

    acc = fmaxf(acc + bias[f], 0.f);
    out[(size_t)node * 128 + f] = f2bf(acc);
}

// ---------------- FC (128->2) + log_softmax, one wave per node ------------
__global__ __launch_bounds__(256) void fc_kernel(const bf16_t* __restrict__ x,
                                                 const float* __restrict__ Wfc,
                                                 const float* __restrict__ bfc,
                                                 float* __restrict__ out) {
    int gid = blockIdx.x * blockDim.x + threadIdx.x;
    int node = gid >> 6;
    int lane = gid & 63;
    if (node >= N_NODES) return;
    float2 v = bfpair(((const unsigned*)(x + (size_t)node * 128))[lane]);
    int k0 = lane * 2;
    float a0 = v.x * Wfc[k0 * 2 + 0] + v.y * Wfc[(k0 + 1) * 2 + 0];
    float a1 = v.x * Wfc[k0 * 2 + 1] + v.y * Wfc[(k0 + 1) * 2 + 1];
#pragma unroll
    for (int off = 32; off > 0; off >>= 1) {
        a0 += __shfl_down(a0, off);
        a1 += __shfl_down(a1, off);
    }
    if (lane == 0) {
        float l0 = a0 + bfc[0];
        float l1 = a1 + bfc[1];
        float m = fmaxf(l0, l1);
        float lse = m + logf(expf(l0 - m) + expf(l1 - m));
        out[(size_t)node * 2 + 0] = l0 - lse;
        out[(size_t)node * 2 + 1] = l1 - lse;
    }
}

extern "C" void kernel_launch(void* const* d_in, const int* in_sizes, int n_in,
                              void* d_out, int out_size, void* d_ws, size_t ws_size,
                              hipStream_t stream) {
    const float* x   = (const float*)d_in[0];
    const int*   ei  = (const int*)d_in[1];
    const float* W1  = (const float*)d_in[2];
    const float* b1  = (const float*)d_in[3];
    const float* W2  = (const float*)d_in[4];
    const float* b2  = (const float*)d_in[5];
    const float* Wfc = (const float*)d_in[6];
    const float* bfc = (const float*)d_in[7];
    float* out = (float*)d_out;

    const int* src = ei;
    const int* dst = ei + E_EDGES;

    // workspace: 256B-aligned carve
    char* wp = (char*)d_ws;
    auto carve = [&](size_t bytes) -> char* {
        char* p = wp;
        wp += (bytes + 255) & ~(size_t)255;
        return p;
    };
    int*    cnt    = (int*)carve(N_NODES * 4);
    int*    rowptr = (int*)carve((N_NODES + 1) * 4);
    int*    cursor = (int*)carve(N_NODES * 4);
    int*    bsum   = (int*)carve(128 * 4);
    int2*   emeta  = (int2*)carve((size_t)E_EDGES * 8);
    float*  dinv   = (float*)carve(N_NODES * 4);
    bf16_t* hbuf   = (bf16_t*)carve((size_t)N_NODES * FDIM * 2);
    bf16_t* x2buf  = (bf16_t*)carve((size_t)N_NODES * FDIM * 2);
    bf16_t* x3buf  = (bf16_t*)carve((size_t)N_NODES * FDIM * 2);
    bf16_t* Wt1    = (bf16_t*)carve(128 * 128 * 2);
    bf16_t* Wt2    = (bf16_t*)carve(128 * 128 * 2);

    const int NN_BLK = (N_NODES + 255) / 256;
    const int NODE_WAVE_BLK = (N_NODES * 64 + 255) / 256;   // 25000
    const int EDGE_PASS_BLK = ((E_EDGES + 255) / 256) * NPASS;   // 50000
    const int GEMM_BLK = (N_NODES + 63) / 64;                     // 1563
    const int AGG_BLK = 50000;   // 2 halves x 25000 node-groups of 4

    // ---- build CSR (dst-sorted) + dinv ----
    hipMemsetAsync(cnt, 0, N_NODES * sizeof(int), stream);
    hipMemsetAsync(cursor, 0, N_NODES * sizeof(int), stream);
    hist_kernel<<<EDGE_PASS_BLK, 256, 0, stream>>>(dst, cnt);
    scan1<<<NSCAN_BLKS, 256, 0, stream>>>(cnt, rowptr, bsum);
    scan2<<<1, 128, 0, stream>>>(bsum);
    scan3<<<NN_BLK, 256, 0, stream>>>(rowptr, bsum, cnt, dinv);
    scatter_kernel<<<EDGE_PASS_BLK, 256, 0, stream>>>(src, dst, rowptr, dinv,
                                                      cursor, emeta);

    // ---- weight transpose/convert ----
    wcvt_kernel<<<64, 256, 0, stream>>>(W1, Wt1);
    wcvt_kernel<<<64, 256, 0, stream>>>(W2, Wt2);

    // ---- layer 1 ----
    gemm_mfma<true><<<GEMM_BLK, 256, 0, stream>>>(x, Wt1, hbuf);
    agg_half_kernel<<<AGG_BLK, 256, 0, stream>>>(rowptr, emeta, dinv, hbuf, b1, x2buf);

    // ---- layer 2 ----
    gemm_mfma<false><<<GEMM_BLK, 256, 0, stream>>>(x2buf, Wt2, hbuf);
    agg_half_kernel<<<AGG_BLK, 256, 0, stream>>>(rowptr, emeta, dinv, hbuf, b2, x3buf);

    // ---- FC + log_softmax ----
    fc_kernel<<<NODE_WAVE_BLK, 256, 0, stream>>>(x3buf, Wfc, bfc, out);
}

// Round 9
// 455.998 us; speedup vs baseline: 1.3758x; 1.3758x over previous
//
#include <hip/hip_runtime.h>
#include <math.h>

#define N_NODES 100000
#define FDIM 128
#define E_EDGES 1600000
#define NSCAN_BLKS ((N_NODES + 1023) / 1024)   // 98
#define NPASS 8
#define PASS_NODES 12500                        // N_NODES / NPASS exactly

typedef unsigned short bf16_t;
typedef __attribute__((ext_vector_type(8))) short short8;
typedef __attribute__((ext_vector_type(4))) float f32x4;

__device__ inline bf16_t f2bf(float f) {
    unsigned int u = __float_as_uint(f);
    return (bf16_t)((u + 0x7fffu + ((u >> 16) & 1u)) >> 16);   // RNE
}
// unpack uint (2 packed bf16) -> float2 (x = low element = even col)
__device__ inline float2 bfpair(unsigned int u) {
    return make_float2(__uint_as_float(u << 16), __uint_as_float(u & 0xffff0000u));
}

// ---------------- in-degree histogram, range-partitioned -------
__global__ __launch_bounds__(256) void hist_kernel(const int* __restrict__ dst,
                                                   int* __restrict__ cnt) {
    int pass = blockIdx.x & (NPASS - 1);
    int e = (blockIdx.x >> 3) * 256 + threadIdx.x;
    if (e >= E_EDGES) return;
    int d = dst[e];
    if ((unsigned)(d - pass * PASS_NODES) < (unsigned)PASS_NODES)
        atomicAdd(&cnt[d], 1);
}

// ---------------- 3-phase exclusive scan: cnt -> rowptr ----------------
__global__ __launch_bounds__(256) void scan1(const int* __restrict__ cnt,
                                             int* __restrict__ excl,
                                             int* __restrict__ bsum) {
    __shared__ int lds[256];
    const int b = blockIdx.x, t = threadIdx.x;
    const int base = b * 1024 + t * 4;
    int v[4];
#pragma unroll
    for (int q = 0; q < 4; ++q) {
        int i = base + q;
        v[q] = (i < N_NODES) ? cnt[i] : 0;
    }
    int tsum = v[0] + v[1] + v[2] + v[3];
    lds[t] = tsum;
    __syncthreads();
    for (int off = 1; off < 256; off <<= 1) {
        int x = lds[t];
        int y = (t >= off) ? lds[t - off] : 0;
        __syncthreads();
        lds[t] = x + y;
        __syncthreads();
    }
    int texcl = lds[t] - tsum;
    if (t == 255) bsum[b] = lds[t];
    int run = texcl;
#pragma unroll
    for (int q = 0; q < 4; ++q) {
        int i = base + q;
        if (i < N_NODES) excl[i] = run;
        run += v[q];
    }
}

__global__ __launch_bounds__(128) void scan2(int* __restrict__ bsum) {
    __shared__ int lds[128];
    const int t = threadIdx.x;
    int v = (t < NSCAN_BLKS) ? bsum[t] : 0;
    lds[t] = v;
    __syncthreads();
    for (int off = 1; off < 128; off <<= 1) {
        int x = lds[t];
        int y = (t >= off) ? lds[t - off] : 0;
        __syncthreads();
        lds[t] = x + y;
        __syncthreads();
    }
    if (t < NSCAN_BLKS) bsum[t] = lds[t] - v;   // exclusive
}

// add block offsets + compute dinv + zero cursor + close rowptr
__global__ __launch_bounds__(256) void scan3(int* __restrict__ rowptr,
                                             const int* __restrict__ bsum,
                                             const int* __restrict__ cnt,
                                             float* __restrict__ dinv,
                                             int* __restrict__ cursor) {
    int i = blockIdx.x * blockDim.x + threadIdx.x;
    if (i < N_NODES) {
        rowptr[i] += bsum[i >> 10];
        dinv[i] = rsqrtf((float)cnt[i] + 1.0f);
        cursor[i] = 0;
    }
    if (i == 0) rowptr[N_NODES] = E_EDGES;
}

// ------- scatter edges, range-partitioned; store {src, norm} per slot ------
__global__ __launch_bounds__(256) void scatter_kernel(const int* __restrict__ src,
                                                      const int* __restrict__ dst,
                                                      const int* __restrict__ rowptr,
                                                      const float* __restrict__ dinv,
                                                      int* __restrict__ cursor,
                                                      int2* __restrict__ emeta) {
    int pass = blockIdx.x & (NPASS - 1);
    int e = (blockIdx.x >> 3) * 256 + threadIdx.x;
    if (e >= E_EDGES) return;
    int d = dst[e];
    if ((unsigned)(d - pass * PASS_NODES) < (unsigned)PASS_NODES) {
        int s = src[e];
        int p = rowptr[d] + atomicAdd(&cursor[d], 1);
        float nrm = dinv[s] * dinv[d];
        emeta[p] = make_int2(s, __float_as_int(nrm));
    }
}

// ------- both W [k][c] fp32 -> Wt [c][k] bf16 (B^T layout), one kernel -----
__global__ __launch_bounds__(256) void wcvt_kernel(const float* __restrict__ W1,
                                                   bf16_t* __restrict__ Wt1,
                                                   const float* __restrict__ W2,
                                                   bf16_t* __restrict__ Wt2) {
    int gid = blockIdx.x * 256 + threadIdx.x;   // over 32768
    const float* W = (gid < 16384) ? W1 : W2;
    bf16_t* Wt = (gid < 16384) ? Wt1 : Wt2;
    int idx = gid & 16383;
    int k = idx >> 7, c = idx & 127;
    Wt[c * 128 + k] = f2bf(W[idx]);
}

// ---------------- MFMA GEMM: H(bf16) = A @ Wt^T, 2 row-tiles per wave ------
// Wave computes rows [rowbase, rowbase+32) x all 128 cols; B-frags shared
// across the two 16-row tiles (halves Wt traffic, 2x MFMA per B-load).
template <bool A_IS_F32>
__global__ __launch_bounds__(256) void gemm_mfma(const void* __restrict__ Aptr,
                                                 const bf16_t* __restrict__ Wt,
                                                 bf16_t* __restrict__ H) {
    const int tid = threadIdx.x;
    const int wave = tid >> 6;
    const int l = tid & 63;
    const int r = l & 15;          // A row / B col within tile
    const int g = l >> 4;          // k-group (0..3)
    const int rowbase = (blockIdx.x * 8 + wave * 2) * 16;
    const int arow0 = min(rowbase + r, N_NODES - 1);
    const int arow1 = min(rowbase + 16 + r, N_NODES - 1);

    f32x4 acc0[8], acc1[8];
#pragma unroll
    for (int ct = 0; ct < 8; ++ct) {
        acc0[ct] = (f32x4){0.f, 0.f, 0.f, 0.f};
        acc1[ct] = (f32x4){0.f, 0.f, 0.f, 0.f};
    }

#pragma unroll
    for (int ks = 0; ks < 4; ++ks) {
        const int kbase = ks * 32 + g * 8;
        short8 a0, a1;
        if constexpr (A_IS_F32) {
            const float* X = (const float*)Aptr;
            const float4 p0 = *((const float4*)(X + (size_t)arow0 * 128 + kbase));
            const float4 p1 = *((const float4*)(X + (size_t)arow0 * 128 + kbase + 4));
            const float4 q0 = *((const float4*)(X + (size_t)arow1 * 128 + kbase));
            const float4 q1 = *((const float4*)(X + (size_t)arow1 * 128 + kbase + 4));
            a0[0] = (short)f2bf(p0.x); a0[1] = (short)f2bf(p0.y);
            a0[2] = (short)f2bf(p0.z); a0[3] = (short)f2bf(p0.w);
            a0[4] = (short)f2bf(p1.x); a0[5] = (short)f2bf(p1.y);
            a0[6] = (short)f2bf(p1.z); a0[7] = (short)f2bf(p1.w);
            a1[0] = (short)f2bf(q0.x); a1[1] = (short)f2bf(q0.y);
            a1[2] = (short)f2bf(q0.z); a1[3] = (short)f2bf(q0.w);
            a1[4] = (short)f2bf(q1.x); a1[5] = (short)f2bf(q1.y);
            a1[6] = (short)f2bf(q1.z); a1[7] = (short)f2bf(q1.w);
        } else {
            const bf16_t* X = (const bf16_t*)Aptr;
            a0 = *((const short8*)(X + (size_t)arow0 * 128 + kbase));
            a1 = *((const short8*)(X + (size_t)arow1 * 128 + kbase));
        }
#pragma unroll
        for (int ct = 0; ct < 8; ++ct) {
            short8 b = *((const short8*)(Wt + (ct * 16 + r) * 128 + kbase));
            acc0[ct] = __builtin_amdgcn_mfma_f32_16x16x32_bf16(a0, b, acc0[ct], 0, 0, 0);
            acc1[ct] = __builtin_amdgcn_mfma_f32_16x16x32_bf16(a1, b, acc1[ct], 0, 0, 0);
        }
    }

    // epilogue: D[row = tile + g*4 + j][col = ct*16 + r]
#pragma unroll
    for (int j = 0; j < 4; ++j) {
        const int row0 = rowbase + g * 4 + j;
        if (row0 < N_NODES) {
            bf16_t* hp = H + (size_t)row0 * 128 + r;
#pragma unroll
            for (int ct = 0; ct < 8; ++ct) hp[ct * 16] = f2bf(acc0[ct][j]);
        }
        const int row1 = rowbase + 16 + g * 4 + j;
        if (row1 < N_NODES) {
            bf16_t* hp = H + (size_t)row1 * 128 + r;
#pragma unroll
            for (int ct = 0; ct < 8; ++ct) hp[ct * 16] = f2bf(acc1[ct][j]);
        }
    }
}

// ------- fused gather-aggregate + self-loop + bias + ReLU -> bf16 out ------
// One wave per node, 4 B/lane row loads (full 256 B row per instruction),
// unroll 8 with meta double-buffer.
__global__ __launch_bounds__(256) void agg_kernel(const int* __restrict__ rowptr,
                                                  const int2* __restrict__ emeta,
                                                  const float* __restrict__ dinv,
                                                  const bf16_t* __restrict__ h,
                                                  const float* __restrict__ bias,
                                                  bf16_t* __restrict__ out) {
    int gid = blockIdx.x * blockDim.x + threadIdx.x;
    int node = gid >> 6;
    int lane = gid & 63;
    if (node >= N_NODES) return;
    const unsigned* __restrict__ hu = (const unsigned*)h;

    float dd = dinv[node];
    float2 v = bfpair(hu[(size_t)node * 64 + lane]);
    float sc = dd * dd;
    float accx = v.x * sc, accy = v.y * sc;

    int j = rowptr[node];
    const int end = rowptr[node + 1];

    int2 m0, m1, m2, m3, m4, m5, m6, m7;
    bool have = (j + 8 <= end);
    if (have) {
        m0 = emeta[j + 0]; m1 = emeta[j + 1]; m2 = emeta[j + 2]; m3 = emeta[j + 3];
        m4 = emeta[j + 4]; m5 = emeta[j + 5]; m6 = emeta[j + 6]; m7 = emeta[j + 7];
    }
    while (have) {
        const int jn = j + 8;
        const bool nxt = (jn + 8 <= end);
        int2 t0, t1, t2, t3, t4, t5, t6, t7;
        if (nxt) {
            t0 = emeta[jn + 0]; t1 = emeta[jn + 1]; t2 = emeta[jn + 2]; t3 = emeta[jn + 3];
            t4 = emeta[jn + 4]; t5 = emeta[jn + 5]; t6 = emeta[jn + 6]; t7 = emeta[jn + 7];
        }
        float2 v0 = bfpair(hu[(size_t)m0.x * 64 + lane]);
        float2 v1 = bfpair(hu[(size_t)m1.x * 64 + lane]);
        float2 v2 = bfpair(hu[(size_t)m2.x * 64 + lane]);
        float2 v3 = bfpair(hu[(size_t)m3.x * 64 + lane]);
        float2 v4 = bfpair(hu[(size_t)m4.x * 64 + lane]);
        float2 v5 = bfpair(hu[(size_t)m5.x * 64 + lane]);
        float2 v6 = bfpair(hu[(size_t)m6.x * 64 + lane]);
        float2 v7 = bfpair(hu[(size_t)m7.x * 64 + lane]);
        accx += v0.x * __int_as_float(m0.y) + v1.x * __int_as_float(m1.y)
              + v2.x * __int_as_float(m2.y) + v3.x * __int_as_float(m3.y)
              + v4.x * __int_as_float(m4.y) + v5.x * __int_as_float(m5.y)
              + v6.x * __int_as_float(m6.y) + v7.x * __int_as_float(m7.y);
        accy += v0.y * __int_as_float(m0.y) + v1.y * __int_as_float(m1.y)
              + v2.y * __int_as_float(m2.y) + v3.y * __int_as_float(m3.y)
              + v4.y * __int_as_float(m4.y) + v5.y * __int_as_float(m5.y)
              + v6.y * __int_as_float(m6.y) + v7.y * __int_as_float(m7.y);
        j = jn;
        have = nxt;
        if (nxt) {
            m0 = t0; m1 = t1; m2 = t2; m3 = t3;
            m4 = t4; m5 = t5; m6 = t6; m7 = t7;
        }
    }
    for (; j < end; ++j) {
        int2 m = emeta[j];
        float2 v0 = bfpair(hu[(size_t)m.x * 64 + lane]);
        float n0 = __int_as_float(m.y);
        accx += v0.x * n0;
        accy += v0.y * n0;
    }

    float2 b = ((const float2*)bias)[lane];
    accx = fmaxf(accx + b.x, 0.f);
    accy = fmaxf(accy + b.y, 0.f);
    unsigned o = (unsigned)f2bf(accx) | ((unsigned)f2bf(accy) << 16);
    ((unsigned*)out)[(size_t)node * 64 + lane] = o;
}

// ------- layer-2 agg fused with FC(128->2) + log_softmax ----
__global__ __launch_bounds__(256) void agg_fc_kernel(const int* __restrict__ rowptr,
                                                     const int2* __restrict__ emeta,
                                                     const float* __restrict__ dinv,
                                                     const bf16_t* __restrict__ h,
                                                     const float* __restrict__ bias,
                                                     const float* __restrict__ Wfc,
                                                     const float* __restrict__ bfc,
                                                     float* __restrict__ out) {
    int gid = blockIdx.x * blockDim.x + threadIdx.x;
    int node = gid >> 6;
    int lane = gid & 63;
    if (node >= N_NODES) return;
    const unsigned* __restrict__ hu = (const unsigned*)h;

    float dd = dinv[node];
    float2 v = bfpair(hu[(size_t)node * 64 + lane]);
    float sc = dd * dd;
    float accx = v.x * sc, accy = v.y * sc;

    int j = rowptr[node];
    const int end = rowptr[node + 1];

    int2 m0, m1, m2, m3, m4, m5, m6, m7;
    bool have = (j + 8 <= end);
    if (have) {
        m0 = emeta[j + 0]; m1 = emeta[j + 1]; m2 = emeta[j + 2]; m3 = emeta[j + 3];
        m4 = emeta[j + 4]; m5 = emeta[j + 5]; m6 = emeta[j + 6]; m7 = emeta[j + 7];
    }
    while (have) {
        const int jn = j + 8;
        const bool nxt = (jn + 8 <= end);
        int2 t0, t1, t2, t3, t4, t5, t6, t7;
        if (nxt) {
            t0 = emeta[jn + 0]; t1 = emeta[jn + 1]; t2 = emeta[jn + 2]; t3 = emeta[jn + 3];
            t4 = emeta[jn + 4]; t5 = emeta[jn + 5]; t6 = emeta[jn + 6]; t7 = emeta[jn + 7];
        }
        float2 v0 = bfpair(hu[(size_t)m0.x * 64 + lane]);
        float2 v1 = bfpair(hu[(size_t)m1.x * 64 + lane]);
        float2 v2 = bfpair(hu[(size_t)m2.x * 64 + lane]);
        float2 v3 = bfpair(hu[(size_t)m3.x * 64 + lane]);
        float2 v4 = bfpair(hu[(size_t)m4.x * 64 + lane]);
        float2 v5 = bfpair(hu[(size_t)m5.x * 64 + lane]);
        float2 v6 = bfpair(hu[(size_t)m6.x * 64 + lane]);
        float2 v7 = bfpair(hu[(size_t)m7.x * 64 + lane]);
        accx += v0.x * __int_as_float(m0.y) + v1.x * __int_as_float(m1.y)
              + v2.x * __int_as_float(m2.y) + v3.x * __int_as_float(m3.y)
              + v4.x * __int_as_float(m4.y) + v5.x * __int_as_float(m5.y)
              + v6.x * __int_as_float(m6.y) + v7.x * __int_as_float(m7.y);
        accy += v0.y * __int_as_float(m0.y) + v1.y * __int_as_float(m1.y)
              + v2.y * __int_as_float(m2.y) + v3.y * __int_as_float(m3.y)
              + v4.y * __int_as_float(m4.y) + v5.y * __int_as_float(m5.y)
              + v6.y * __int_as_float(m6.y) + v7.y * __int_as_float(m7.y);
        j = jn;
        have = nxt;
        if (nxt) {
            m0 = t0; m1 = t1; m2 = t2; m3 = t3;
            m4 = t4; m5 = t5; m6 = t6; m7 = t7;
        }
    }
    for (; j < end; ++j) {
        int2 m = emeta[j];
        float2 v0 = bfpair(hu[(size_t)m.x * 64 + lane]);
        float n0 = __int_as_float(m.y);
        accx += v0.x * n0;
        accy += v0.y * n0;
    }

    float2 b = ((const float2*)bias)[lane];
    accx = fmaxf(accx + b.x, 0.f);
    accy = fmaxf(accy + b.y, 0.f);
    // FC: lane covers k = 2*lane, 2*lane+1 ; Wfc is [128][2] row-major
    int k0 = lane * 2;
    float a0 = accx * Wfc[k0 * 2 + 0] + accy * Wfc[(k0 + 1) * 2 + 0];
    float a1 = accx * Wfc[k0 * 2 + 1] + accy * Wfc[(k0 + 1) * 2 + 1];
#pragma unroll
    for (int off = 32; off > 0; off >>= 1) {
        a0 += __shfl_down(a0, off);
        a1 += __shfl_down(a1, off);
    }
    if (lane == 0) {
        float l0 = a0 + bfc[0];
        float l1 = a1 + bfc[1];
        float m = fmaxf(l0, l1);
        float lse = m + logf(expf(l0 - m) + expf(l1 - m));
        out[(size_t)node * 2 + 0] = l0 - lse;
        out[(size_t)node * 2 + 1] = l1 - lse;
    }
}

extern "C" void kernel_launch(void* const* d_in, const int* in_sizes, int n_in,
                              void* d_out, int out_size, void* d_ws, size_t ws_size,
                              hipStream_t stream) {
    const float* x   = (const float*)d_in[0];
    const int*   ei  = (const int*)d_in[1];
    const float* W1  = (const float*)d_in[2];
    const float* b1  = (const float*)d_in[3];
    const float* W2  = (const float*)d_in[4];
    const float* b2  = (const float*)d_in[5];
    const float* Wfc = (const float*)d_in[6];
    const float* bfc = (const float*)d_in[7];
    float* out = (float*)d_out;

    const int* src = ei;
    const int* dst = ei + E_EDGES;

    // workspace: 256B-aligned carve
    char* wp = (char*)d_ws;
    auto carve = [&](size_t bytes) -> char* {
        char* p = wp;
        wp += (bytes + 255) & ~(size_t)255;
        return p;
    };
    int*    cnt    = (int*)carve(N_NODES * 4);
    int*    rowptr = (int*)carve((N_NODES + 1) * 4);
    int*    cursor = (int*)carve(N_NODES * 4);
    int*    bsum   = (int*)carve(128 * 4);
    int2*   emeta  = (int2*)carve((size_t)E_EDGES * 8);
    float*  dinv   = (float*)carve(N_NODES * 4);
    bf16_t* hbuf   = (bf16_t*)carve((size_t)N_NODES * FDIM * 2);
    bf16_t* x2buf  = (bf16_t*)carve((size_t)N_NODES * FDIM * 2);
    bf16_t* Wt1    = (bf16_t*)carve(128 * 128 * 2);
    bf16_t* Wt2    = (bf16_t*)carve(128 * 128 * 2);

    const int NN_BLK = (N_NODES + 255) / 256;
    const int NODE_WAVE_BLK = (N_NODES * 64 + 255) / 256;        // 25000
    const int EDGE_PASS_BLK = ((E_EDGES + 255) / 256) * NPASS;   // 50000
    const int GEMM_BLK = (N_NODES + 127) / 128;                  // 782

    // ---- build CSR (dst-sorted) + dinv ----
    hipMemsetAsync(cnt, 0, N_NODES * sizeof(int), stream);
    hist_kernel<<<EDGE_PASS_BLK, 256, 0, stream>>>(dst, cnt);
    scan1<<<NSCAN_BLKS, 256, 0, stream>>>(cnt, rowptr, bsum);
    scan2<<<1, 128, 0, stream>>>(bsum);
    scan3<<<NN_BLK, 256, 0, stream>>>(rowptr, bsum, cnt, dinv, cursor);
    scatter_kernel<<<EDGE_PASS_BLK, 256, 0, stream>>>(src, dst, rowptr, dinv,
                                                      cursor, emeta);

    // ---- weight transpose/convert (both) ----
    wcvt_kernel<<<128, 256, 0, stream>>>(W1, Wt1, W2, Wt2);

    // ---- layer 1 ----
    gemm_mfma<true><<<GEMM_BLK, 256, 0, stream>>>(x, Wt1, hbuf);
    agg_kernel<<<NODE_WAVE_BLK, 256, 0, stream>>>(rowptr, emeta, dinv, hbuf, b1, x2buf);

    // ---- layer 2 (agg fused with FC + log_softmax) ----
    gemm_mfma<false><<<GEMM_BLK, 256, 0, stream>>>(x2buf, Wt2, hbuf);
    agg_fc_kernel<<<NODE_WAVE_BLK, 256, 0, stream>>>(rowptr, emeta, dinv, hbuf, b2,
                                                     Wfc, bfc, out);
}